// Round 7
// baseline (645.095 us; speedup 1.0000x reference)
//
#include <hip/hip_runtime.h>

typedef __bf16 bf16_t;
typedef bf16_t bf16x4 __attribute__((ext_vector_type(4)));
typedef bf16_t bf16x8 __attribute__((ext_vector_type(8)));
typedef float floatx4 __attribute__((ext_vector_type(4)));
typedef float floatx16 __attribute__((ext_vector_type(16)));

#define EPSF 1e-5f
#define DEV static __device__ __forceinline__

DEV bf16x8 cvt8(float4 a, float4 b) {
    bf16x8 r = { (bf16_t)a.x, (bf16_t)a.y, (bf16_t)a.z, (bf16_t)a.w,
                 (bf16_t)b.x, (bf16_t)b.y, (bf16_t)b.z, (bf16_t)b.w };
    return r;
}

// ---------------------------------------------------------------------------
// K0: swizzle weights into MFMA B-fragment order (bf16).
// 16-wide (16x16x32): idx=((t*4+s)*64+l)*8+j -> W[(s*32+(l>>4)*8+j)*128 + t*16+(l&15)]
//   W_in@0, W_m1@16384, W_m2@32768, W_ctx2@49152   (16384 each)
// 32-wide (32x32x16): idx=((t*16+s)*64+l)*8+j -> W[(s*16+(l>>5)*8+j)*128 + t*32+(l&31)]
//   W_ctx1@65536 (32768).  Total 98304 bf16.
// ---------------------------------------------------------------------------
__global__ __launch_bounds__(256) void k_prep(
    const float* __restrict__ W_in, const float* __restrict__ W_m1,
    const float* __restrict__ W_m2, const float* __restrict__ W_ctx2,
    const float* __restrict__ W_ctx1, bf16_t* __restrict__ sw)
{
    int idx = blockIdx.x * 256 + threadIdx.x;   // grid exactly 98304
    int j = idx & 7, l = (idx >> 3) & 63;
    float v;
    if (idx < 65536) {
        const float* W = (idx < 16384) ? W_in
                       : (idx < 32768) ? W_m1
                       : (idx < 49152) ? W_m2 : W_ctx2;
        int local = idx & 16383;
        int rest = local >> 9;          // [0,32)
        int s = rest & 3, t = rest >> 2;
        int k = s * 32 + (l >> 4) * 8 + j;
        int n = t * 16 + (l & 15);
        v = W[k * 128 + n];
    } else {
        int local = idx - 65536;
        int rest = local >> 9;          // [0,64)
        int s = rest & 15, t = rest >> 4;
        int k = s * 16 + (l >> 5) * 8 + j;
        int n = t * 32 + (l & 31);
        v = W_ctx1[k * 128 + n];
    }
    sw[idx] = (bf16_t)v;
}

// ---------------------------------------------------------------------------
// CSR construction
// ---------------------------------------------------------------------------
__global__ void k_zero(int* __restrict__ p, int n) {
    int i = blockIdx.x * 256 + threadIdx.x;
    if (i < n) p[i] = 0;
}

__global__ void k_hist(const int* __restrict__ wi, int* __restrict__ deg, int E) {
    int i = blockIdx.x * 256 + threadIdx.x;
    if (i < E) atomicAdd(&deg[wi[i]], 1);
}

__global__ __launch_bounds__(256) void k_scan_block(int* __restrict__ a,
                                                    int* __restrict__ bsum, int n) {
    __shared__ int wsum[4];
    int tid = threadIdx.x, lane = tid & 63, wv = tid >> 6;
    int base = blockIdx.x * 1024 + tid * 4;
    int v[4];
#pragma unroll
    for (int i = 0; i < 4; ++i) v[i] = (base + i < n) ? a[base + i] : 0;
    int tsum = v[0] + v[1] + v[2] + v[3];
    int sc = tsum;
#pragma unroll
    for (int d = 1; d < 64; d <<= 1) {
        int o = __shfl_up(sc, d);
        if (lane >= d) sc += o;
    }
    if (lane == 63) wsum[wv] = sc;
    __syncthreads();
    int wadd = 0;
    for (int w = 0; w < wv; ++w) wadd += wsum[w];
    int run = sc - tsum + wadd;
#pragma unroll
    for (int i = 0; i < 4; ++i) {
        int t = v[i];
        if (base + i < n) a[base + i] = run;
        run += t;
    }
    if (tid == 255) bsum[blockIdx.x] = wadd + sc;
}

__global__ __launch_bounds__(128) void k_scan_top(int* __restrict__ bsum, int nb) {
    __shared__ int s[128];
    int tid = threadIdx.x;
    int v = (tid < nb) ? bsum[tid] : 0;
    s[tid] = v;
    __syncthreads();
    for (int d = 1; d < 128; d <<= 1) {
        int t = (tid >= d) ? s[tid - d] : 0;
        __syncthreads();
        s[tid] += t;
        __syncthreads();
    }
    if (tid < nb) bsum[tid] = s[tid] - v;
}

__global__ void k_scan_add(int* __restrict__ a, int* __restrict__ cursor,
                           const int* __restrict__ bsum, int n) {
    int i = blockIdx.x * 256 + threadIdx.x;
    if (i < n) { int v = a[i] + bsum[i >> 10]; a[i] = v; cursor[i] = v; }
}

__global__ void k_bucket(const int* __restrict__ wi, int* __restrict__ cursor,
                         int* __restrict__ perm, int E) {
    int e = blockIdx.x * 256 + threadIdx.x;
    if (e < E) { int p = atomicAdd(&cursor[wi[e]], 1); perm[e] = p; }
}

// GroupNorm on 16x16 MFMA C-layout accumulators.
DEV void gn_rows(floatx4* acc, int lane, const float* __restrict__ gamma,
                 const float* __restrict__ beta, bool do_relu)
{
    int m = lane & 15;
    float s1[4] = {0.f,0.f,0.f,0.f}, s2[4] = {0.f,0.f,0.f,0.f};
#pragma unroll
    for (int t = 0; t < 8; ++t)
#pragma unroll
        for (int rr = 0; rr < 4; ++rr) { float v = acc[t][rr]; s1[rr] += v; s2[rr] += v*v; }
#pragma unroll
    for (int mask = 1; mask <= 8; mask <<= 1)
#pragma unroll
        for (int rr = 0; rr < 4; ++rr) {
            s1[rr] += __shfl_xor(s1[rr], mask);
            s2[rr] += __shfl_xor(s2[rr], mask);
        }
    float mean[4], inv[4];
#pragma unroll
    for (int rr = 0; rr < 4; ++rr) {
        mean[rr] = s1[rr] * (1.f/128.f);
        float var = s2[rr] * (1.f/128.f) - mean[rr]*mean[rr];
        inv[rr] = rsqrtf(var + EPSF);
    }
#pragma unroll
    for (int t = 0; t < 8; ++t) {
        int n = t*16 + m;
        float ga = gamma[n], be = beta[n];
#pragma unroll
        for (int rr = 0; rr < 4; ++rr) {
            float v = (acc[t][rr] - mean[rr]) * inv[rr] * ga + be;
            acc[t][rr] = do_relu ? fmaxf(v, 0.f) : v;
        }
    }
}

// ---------------------------------------------------------------------------
// K2: per-edge h = relu(GN(cat @ W_ctx1)) -> hctx[perm[e]] (bf16, CSR order).
// GEMM2 removed via linearity (done on aggregated rows in k_out).
// 1 wave / 32 edges; pass0 A-frags loaded DIRECT from cfeat (no LDS stage).
// ---------------------------------------------------------------------------
__global__ __launch_bounds__(64, 4) void k_edge(
    const float* __restrict__ cfeat, const float* __restrict__ cpose,
    const float* __restrict__ tpose, const int* __restrict__ hi,
    const int* __restrict__ wi, const float* __restrict__ W_rp,
    const float* __restrict__ b_rp, const float* __restrict__ g_ctx,
    const float* __restrict__ be_ctx, const bf16_t* __restrict__ swC1,
    const int* __restrict__ perm, bf16_t* __restrict__ hctx, int E)
{
    __shared__ alignas(16) bf16_t H[32 * 136];
    int lane = threadIdx.x;
    int eb = blockIdx.x * 32;
    int m = lane & 31, half = lane >> 5;
    int r2 = lane >> 1, cq = (lane & 1) * 64;

    int em = min(eb + m, E - 1);
    int cim = hi[em];
    int e2 = min(eb + r2, E - 1);
    int ci2 = hi[e2], ti2 = wi[e2];
    int pdst = (eb + r2 < E) ? perm[eb + r2] : -1;

    // issue first gather loads (depth-4 prefetch window)
    const float4* arow = (const float4*)(cfeat + (size_t)cim * 128);
    float4 pf[4][2];
#pragma unroll
    for (int s = 0; s < 4; ++s) {
        pf[s][0] = arow[s * 4 + half * 2];
        pf[s][1] = arow[s * 4 + half * 2 + 1];
    }

    // relpose features -> H cols 0..127 (global k 128..255); VALU overlaps loads
    {
        float4 cp = ((const float4*)cpose)[ci2];
        float4 tp = ((const float4*)tpose)[ti2];
        float d0 = cp.x - tp.x, d1 = cp.y - tp.y, d2 = cp.z - tp.z, d3 = cp.w - tp.w;
#pragma unroll
        for (int i = 0; i < 16; ++i) {
            int c = cq + i * 4;
            float4 w0 = *(const float4*)(W_rp + c);
            float4 w1 = *(const float4*)(W_rp + 128 + c);
            float4 w2 = *(const float4*)(W_rp + 256 + c);
            float4 w3 = *(const float4*)(W_rp + 384 + c);
            float4 bb = *(const float4*)(b_rp + c);
            float o0 = fmaxf(d0*w0.x + d1*w1.x + d2*w2.x + d3*w3.x + bb.x, 0.f);
            float o1 = fmaxf(d0*w0.y + d1*w1.y + d2*w2.y + d3*w3.y + bb.y, 0.f);
            float o2 = fmaxf(d0*w0.z + d1*w1.z + d2*w2.z + d3*w3.z + bb.z, 0.f);
            float o3 = fmaxf(d0*w0.w + d1*w1.w + d2*w2.w + d3*w3.w + bb.w, 0.f);
            bf16x4 pk = { (bf16_t)o0, (bf16_t)o1, (bf16_t)o2, (bf16_t)o3 };
            *(bf16x4*)&H[r2 * 136 + c] = pk;
        }
    }

    floatx16 acc[4];
#pragma unroll
    for (int n = 0; n < 4; ++n)
#pragma unroll
        for (int i = 0; i < 16; ++i) acc[n][i] = 0.f;

    // pass 0: k = 0..127 direct from registers
#pragma unroll
    for (int s = 0; s < 8; ++s) {
        bf16x8 a = cvt8(pf[s & 3][0], pf[s & 3][1]);
        if (s + 4 < 8) {
            pf[s & 3][0] = arow[(s + 4) * 4 + half * 2];
            pf[s & 3][1] = arow[(s + 4) * 4 + half * 2 + 1];
        }
#pragma unroll
        for (int n = 0; n < 4; ++n) {
            bf16x8 bF = *(const bf16x8*)&swC1[(size_t)((n * 16 + s) * 64 + lane) * 8];
            acc[n] = __builtin_amdgcn_mfma_f32_32x32x16_bf16(a, bF, acc[n], 0, 0, 0);
        }
    }
    __syncthreads();
    // pass 1: k = 128..255 from H
#pragma unroll
    for (int s = 0; s < 8; ++s) {
        bf16x8 a = *(const bf16x8*)&H[m * 136 + s * 16 + half * 8];
#pragma unroll
        for (int n = 0; n < 4; ++n) {
            bf16x8 bF = *(const bf16x8*)&swC1[(size_t)((n * 16 + 8 + s) * 64 + lane) * 8];
            acc[n] = __builtin_amdgcn_mfma_f32_32x32x16_bf16(a, bF, acc[n], 0, 0, 0);
        }
    }
    __syncthreads();

    // bounce pre-GN h to H row-major. C-layout: col=n*32+m, row=(reg&3)+8*(reg>>2)+4*half
#pragma unroll
    for (int n = 0; n < 4; ++n)
#pragma unroll
        for (int reg = 0; reg < 16; ++reg) {
            int rl = (reg & 3) + 8 * (reg >> 2) + 4 * half;
            H[rl * 136 + n * 32 + m] = (bf16_t)acc[n][reg];
        }
    __syncthreads();

    // GN + ReLU, store straight to hctx[perm]
    {
        float s1 = 0.f, s2 = 0.f;
        bf16x8 hv[8];
#pragma unroll
        for (int i = 0; i < 8; ++i) {
            hv[i] = *(const bf16x8*)&H[r2 * 136 + cq + i * 8];
#pragma unroll
            for (int j = 0; j < 8; ++j) { float f = (float)hv[i][j]; s1 += f; s2 += f * f; }
        }
        s1 += __shfl_xor(s1, 1);
        s2 += __shfl_xor(s2, 1);
        float mean = s1 * (1.f/128.f);
        float inv = rsqrtf(s2 * (1.f/128.f) - mean * mean + EPSF);
        bf16_t* dst = hctx + (size_t)max(pdst, 0) * 128 + cq;
#pragma unroll
        for (int i = 0; i < 8; ++i) {
            int c = cq + i * 8;
            float4 g0 = *(const float4*)(g_ctx + c), g1 = *(const float4*)(g_ctx + c + 4);
            float4 b0 = *(const float4*)(be_ctx + c), b1 = *(const float4*)(be_ctx + c + 4);
            float ga[8] = {g0.x,g0.y,g0.z,g0.w,g1.x,g1.y,g1.z,g1.w};
            float be[8] = {b0.x,b0.y,b0.z,b0.w,b1.x,b1.y,b1.z,b1.w};
            bf16x8 o8;
#pragma unroll
            for (int j = 0; j < 8; ++j)
                o8[j] = (bf16_t)fmaxf(((float)hv[i][j] - mean) * inv * ga[j] + be[j], 0.f);
            if (pdst >= 0) *(bf16x8*)(dst + i * 8) = o8;
        }
    }
}

// ---------------------------------------------------------------------------
// K2b: segmented sum of CSR-ordered hctx -> hsum[Nt,128] f32.
// Block = 256 thr = 64 targets; streams contiguous rows through LDS in
// 64-row chunks (fully coalesced; a row = 16 uint4), per-target sums in regs.
// ---------------------------------------------------------------------------
__global__ __launch_bounds__(256) void k_aggr(
    const bf16_t* __restrict__ hctx, const int* __restrict__ start,
    float* __restrict__ hsum, int Nt, int E)
{
    __shared__ alignas(16) bf16_t L[64 * 136];
    __shared__ int sS[65];
    int tid = threadIdx.x;
    int t0 = blockIdx.x * 64;
    if (tid < 65) {
        int t = t0 + tid;
        sS[tid] = (t < Nt) ? start[t] : E;
    }
    __syncthreads();
    int r0 = sS[0], r1 = sS[64];
    int tl = tid >> 2, cc = (tid & 3) * 32;
    int ms = sS[tl], me = sS[tl + 1];
    float acc[32];
#pragma unroll
    for (int i = 0; i < 32; ++i) acc[i] = 0.f;
    const uint4* src = (const uint4*)hctx;   // 16 uint4 per 128-bf16 row

    for (int c = r0; c < r1; c += 64) {
        int nr = min(64, r1 - c);
        int nf = nr * 16;                    // uint4 fragments this chunk
#pragma unroll
        for (int k = 0; k < 4; ++k) {
            int f = tid + k * 256;
            if (f < nf) {
                uint4 v = src[(size_t)c * 16 + f];
                *(uint4*)&L[(f >> 4) * 136 + (f & 15) * 8] = v;
            }
        }
        __syncthreads();
        int lo = max(ms, c), hi2 = min(me, c + nr);
        for (int gr = lo; gr < hi2; ++gr) {
            int lr = gr - c;
#pragma unroll
            for (int i = 0; i < 4; ++i) {
                bf16x8 h8 = *(const bf16x8*)&L[lr * 136 + cc + i * 8];
#pragma unroll
                for (int j = 0; j < 8; ++j) acc[i * 8 + j] += (float)h8[j];
            }
        }
        __syncthreads();
    }
    if (t0 + tl < Nt) {
        float* dst = hsum + (size_t)(t0 + tl) * 128 + cc;
#pragma unroll
        for (int i = 0; i < 8; ++i)
            *(float4*)&dst[i * 4] = make_float4(acc[i*4], acc[i*4+1], acc[i*4+2], acc[i*4+3]);
    }
}

// ---------------------------------------------------------------------------
// K3: acc = tfeat@W_in + hsum@W_ctx2 (direct-load A-frags), then
// relu(GN(...)) @ W_m1 -> GN -> @ W_m2 -> GN -> +identity -> relu.
// ---------------------------------------------------------------------------
__global__ __launch_bounds__(256) void k_out(
    const float* __restrict__ tfeat, const float* __restrict__ hsum,
    const float* __restrict__ g_n, const float* __restrict__ be_n,
    const float* __restrict__ g_m1, const float* __restrict__ be_m1,
    const float* __restrict__ g_m2, const float* __restrict__ be_m2,
    const bf16_t* __restrict__ swIn, const bf16_t* __restrict__ swC2,
    const bf16_t* __restrict__ swM1, const bf16_t* __restrict__ swM2,
    float* __restrict__ out, int Nt)
{
    __shared__ alignas(16) bf16_t sA[4][2048];
    int tid = threadIdx.x, lane = tid & 63, wave = tid >> 6;
    int tb = (blockIdx.x * 4 + wave) * 16;
    int m = lane & 15, g = lane >> 4;
    int grow = min(tb + m, Nt - 1);
    const float4* trow = (const float4*)(tfeat + (size_t)grow * 128);
    const float4* hrow = (const float4*)(hsum + (size_t)grow * 128);

    floatx4 acc[8];
#pragma unroll
    for (int t = 0; t < 8; ++t) acc[t] = floatx4{0.f,0.f,0.f,0.f};

#pragma unroll
    for (int s = 0; s < 4; ++s) {
        float4 t0 = trow[s * 8 + g * 2], t1 = trow[s * 8 + g * 2 + 1];
        float4 h0 = hrow[s * 8 + g * 2], h1 = hrow[s * 8 + g * 2 + 1];
        bf16x8 aT = cvt8(t0, t1);
        bf16x8 aH = cvt8(h0, h1);
#pragma unroll
        for (int t = 0; t < 8; ++t) {
            bf16x8 bI = *(const bf16x8*)&swIn[((t*4+s)*64 + lane)*8];
            acc[t] = __builtin_amdgcn_mfma_f32_16x16x32_bf16(aT, bI, acc[t], 0, 0, 0);
            bf16x8 bC = *(const bf16x8*)&swC2[((t*4+s)*64 + lane)*8];
            acc[t] = __builtin_amdgcn_mfma_f32_16x16x32_bf16(aH, bC, acc[t], 0, 0, 0);
        }
    }
    gn_rows(acc, lane, g_n, be_n, true);

    // bounce -> A-frag, GEMM m1
#pragma unroll
    for (int t = 0; t < 8; ++t) {
        int n = t*16 + m;
        int s = n >> 5, q = (n >> 3) & 3, j = n & 7;
#pragma unroll
        for (int rr = 0; rr < 4; ++rr)
            sA[wave][(s*64 + q*16 + (g*4+rr))*8 + j] = (bf16_t)acc[t][rr];
    }
    __syncthreads();
    bf16x8 aF[4];
#pragma unroll
    for (int s = 0; s < 4; ++s) aF[s] = *(const bf16x8*)&sA[wave][(s*64 + lane)*8];
#pragma unroll
    for (int t = 0; t < 8; ++t) {
        floatx4 a = {0.f,0.f,0.f,0.f};
#pragma unroll
        for (int s = 0; s < 4; ++s) {
            bf16x8 bF = *(const bf16x8*)&swM1[((t*4+s)*64 + lane)*8];
            a = __builtin_amdgcn_mfma_f32_16x16x32_bf16(aF[s], bF, a, 0, 0, 0);
        }
        acc[t] = a;
    }
    gn_rows(acc, lane, g_m1, be_m1, true);
    __syncthreads();
#pragma unroll
    for (int t = 0; t < 8; ++t) {
        int n = t*16 + m;
        int s = n >> 5, q = (n >> 3) & 3, j = n & 7;
#pragma unroll
        for (int rr = 0; rr < 4; ++rr)
            sA[wave][(s*64 + q*16 + (g*4+rr))*8 + j] = (bf16_t)acc[t][rr];
    }
    __syncthreads();
#pragma unroll
    for (int s = 0; s < 4; ++s) aF[s] = *(const bf16x8*)&sA[wave][(s*64 + lane)*8];
#pragma unroll
    for (int t = 0; t < 8; ++t) {
        floatx4 a = {0.f,0.f,0.f,0.f};
#pragma unroll
        for (int s = 0; s < 4; ++s) {
            bf16x8 bF = *(const bf16x8*)&swM2[((t*4+s)*64 + lane)*8];
            a = __builtin_amdgcn_mfma_f32_16x16x32_bf16(aF[s], bF, a, 0, 0, 0);
        }
        acc[t] = a;
    }
    gn_rows(acc, lane, g_m2, be_m2, false);
#pragma unroll
    for (int t = 0; t < 8; ++t) {
        int n = t*16 + m;
#pragma unroll
        for (int rr = 0; rr < 4; ++rr) {
            int row = tb + g*4 + rr;
            if (row < Nt) {
                float v = acc[t][rr] + tfeat[(size_t)row*128 + n];
                out[(size_t)row*128 + n] = fmaxf(v, 0.f);
            }
        }
    }
}

// ---------------------------------------------------------------------------
extern "C" void kernel_launch(void* const* d_in, const int* in_sizes, int n_in,
                              void* d_out, int out_size, void* d_ws, size_t ws_size,
                              hipStream_t stream)
{
    const float* cfeat  = (const float*)d_in[0];
    const float* tfeat  = (const float*)d_in[1];
    const float* cpose  = (const float*)d_in[2];
    const float* tpose  = (const float*)d_in[3];
    const int*   hi     = (const int*)d_in[4];
    const int*   wi     = (const int*)d_in[5];
    const float* W_in   = (const float*)d_in[6];
    const float* W_rp   = (const float*)d_in[7];
    const float* b_rp   = (const float*)d_in[8];
    const float* W_ctx1 = (const float*)d_in[9];
    const float* g_ctx  = (const float*)d_in[10];
    const float* be_ctx = (const float*)d_in[11];
    const float* W_ctx2 = (const float*)d_in[12];
    const float* g_n    = (const float*)d_in[13];
    const float* be_n   = (const float*)d_in[14];
    const float* W_m1   = (const float*)d_in[15];
    const float* g_m1   = (const float*)d_in[16];
    const float* be_m1  = (const float*)d_in[17];
    const float* W_m2   = (const float*)d_in[18];
    const float* g_m2   = (const float*)d_in[19];
    const float* be_m2  = (const float*)d_in[20];

    int Nt = in_sizes[1] / 128;
    int E  = in_sizes[4];
    float* outp = (float*)d_out;

    char* w = (char*)d_ws;
    size_t off = 0;
    auto alloc = [&](size_t bytes) { char* p = w + off;
        off = (off + bytes + 255) & ~(size_t)255; return p; };
    float*  hsum   = (float*) alloc((size_t)Nt * 128 * sizeof(float));
    bf16_t* sw     = (bf16_t*)alloc(98304 * sizeof(bf16_t));
    bf16_t* hctx   = (bf16_t*)alloc((size_t)E * 128 * sizeof(bf16_t));
    int*    start  = (int*)   alloc((size_t)Nt * sizeof(int));
    int*    cursor = (int*)   alloc((size_t)Nt * sizeof(int));
    int*    perm   = (int*)   alloc((size_t)E * sizeof(int));
    int*    bsum   = (int*)   alloc(128 * sizeof(int));

    bf16_t* swIn = sw;
    bf16_t* swM1 = sw + 16384;
    bf16_t* swM2 = sw + 32768;
    bf16_t* swC2 = sw + 49152;
    bf16_t* swC1 = sw + 65536;

    int NB = (Nt + 1023) / 1024;

    k_prep<<<384, 256, 0, stream>>>(W_in, W_m1, W_m2, W_ctx2, W_ctx1, sw);
    // CSR build
    k_zero<<<(Nt + 255) / 256, 256, 0, stream>>>(start, Nt);
    k_hist<<<(E + 255) / 256, 256, 0, stream>>>(wi, start, E);
    k_scan_block<<<NB, 256, 0, stream>>>(start, bsum, Nt);
    k_scan_top<<<1, 128, 0, stream>>>(bsum, NB);
    k_scan_add<<<(Nt + 255) / 256, 256, 0, stream>>>(start, cursor, bsum, Nt);
    k_bucket<<<(E + 255) / 256, 256, 0, stream>>>(wi, cursor, perm, E);
    // main pipeline
    k_edge<<<(E + 31) / 32, 64, 0, stream>>>(cfeat, cpose, tpose, hi, wi,
                                             W_rp, b_rp, g_ctx, be_ctx,
                                             swC1, perm, hctx, E);
    k_aggr<<<(Nt + 63) / 64, 256, 0, stream>>>(hctx, start, hsum, Nt, E);
    k_out<<<(Nt + 63) / 64, 256, 0, stream>>>(tfeat, hsum,
                                              g_n, be_n, g_m1, be_m1,
                                              g_m2, be_m2,
                                              swIn, swC2, swM1, swM2, outp, Nt);
}